// Round 6
// baseline (186.306 us; speedup 1.0000x reference)
//
#include <hip/hip_runtime.h>

// Problem constants
#define B_     64
#define HW_    96
#define COUT_  96
#define KK_    75          // CIN*KH*KW
#define KP_    76          // padded K for fp32 im2col (k2)
#define KPAD   96          // padded K for MFMA (3 x 32)
#define HOUT_  48
#define L_     2304        // 48*48
#define LR_    0.02f
#define DELTA_ -0.4f
#define OUT_ELEMS (B_*COUT_*L_)
#define CL2    256                  // k2 l-chunk size
#define CPB2   3                    // l-chunks per k2 block
#define NPART2 (B_*3)               // 192 partial rows
#define PROW2  (COUT_*96 + COUT_)   // 9312 floats: yx[96][96] + yy[96]
#define NT1    2                    // l-tiles per k1 block

typedef __attribute__((ext_vector_type(8))) short short8v;     // 8 bf16
typedef __attribute__((ext_vector_type(4))) float float4v;     // 4 f32 acc
typedef __attribute__((ext_vector_type(4))) unsigned uint4v;   // 16B pack

__device__ __forceinline__ unsigned short f2bf(float f) {  // RNE f32->bf16
  unsigned u = __float_as_uint(f);
  u += 0x7fff + ((u >> 16) & 1);
  return (unsigned short)(u >> 16);
}

// top-2 insert with lax.top_k tiebreak (equal values -> lower channel index)
__device__ __forceinline__ void ins2(float v, int o, float& v1, int& o1,
                                     float& v2, int& o2) {
  bool b1 = (v > v1) || (v == v1 && o < o1);
  bool b2 = (v > v2) || (v == v2 && o < o2);
  if (b1)      { v2 = v1; o2 = o1; v1 = v; o1 = o; }
  else if (b2) { v2 = v;  o2 = o; }
}

__device__ __forceinline__ void im2col_load(const float* __restrict__ xb, int l,
                                            float* __restrict__ pre) {
  const int oh = l / HOUT_, ow = l - oh * HOUT_;
  #pragma unroll
  for (int c = 0; c < 3; ++c) {
    #pragma unroll
    for (int i = 0; i < 5; ++i) {
      int ih = oh * 2 + i - 2;
      bool okh = ((unsigned)ih < (unsigned)HW_);
      #pragma unroll
      for (int j = 0; j < 5; ++j) {
        int iw = ow * 2 + j - 2;
        float v = 0.0f;
        if (okh && ((unsigned)iw < (unsigned)HW_)) v = xb[(c * HW_ + ih) * HW_ + iw];
        pre[c * 25 + i * 5 + j] = v;
      }
    }
  }
  pre[KK_] = 0.0f;
}

// Kernel 0: build stacked bf16 A-matrix [192][96]: rows 0..95 = W, 96..191 = W*|W|.
__global__ __launch_bounds__(256) void k0_prep(const float* __restrict__ w,
                                               unsigned short* __restrict__ wbf) {
  int i = blockIdx.x * 256 + threadIdx.x;
  if (i >= 192 * KPAD) return;
  int row = i / KPAD, k = i - row * KPAD;
  float v = 0.0f;
  if (k < KK_) {
    float ww = w[(row % COUT_) * KK_ + k];
    v = (row < COUT_) ? ww : ww * fabsf(ww);   // sign(w)|w|^2, p=3
  }
  wbf[i] = f2bf(v);
}

// Kernel 1 (v3): pipelined MFMA conv + tot + top-2.
// grid (18, 64), block 256 = 4 waves; block = 2 l-tiles of 64 positions.
// Pipeline: stage(t0); BAR; [load(t1) | mfma(t0) | write(t1) | tail(t0)]; BAR;
// [merge(t0) | mfma(t1) | tail(t1)]; BAR; merge(t1).
// Staging uses b128 ds_writes (8 consecutive k per write, blk^=pos&3 swizzle,
// <=2-way conflicts = free). A-fragments loaded once, reused for both tiles.
__global__ __launch_bounds__(256, 4) void k1_mfma(
    const float* __restrict__ x, const unsigned short* __restrict__ wbf,
    float* __restrict__ out, float4* __restrict__ top2)
{
  __shared__ __align__(16) unsigned short preS[2][64 * KPAD];  // 2 x 12 KB
  __shared__ float4 mrg[2][2][64];                             // 4 KB
  const int tid = threadIdx.x;
  const int b = blockIdx.y;
  const int base_l = blockIdx.x * (64 * NT1);
  const float* xb = x + (size_t)b * (3 * HW_ * HW_);

  const int lane = tid & 63, wq = tid >> 6;
  const int col = lane & 15, g = lane >> 4;
  const int pos = lane;            // staging: position within tile
  const int kbase = wq * 24;       // staging: this thread's k-range base

  // A fragments, loaded once for both tiles
  short8v afr[3][3];
  #pragma unroll
  for (int mt = 0; mt < 3; ++mt)
    #pragma unroll
    for (int kt = 0; kt < 3; ++kt)
      afr[mt][kt] = *(const short8v*)(
          wbf + ((wq * 48 + mt * 16 + col) * KPAD + kt * 32 + g * 8));

  // ---- staging helpers ----
  auto stage_load = [&](int tt, uint4v (&pk)[3]) {
    const int l = base_l + tt * 64 + pos;
    const int oh = l / HOUT_, ow = l - oh * HOUT_;
    const int ihb = 2 * oh - 2, iwb = 2 * ow - 2;
    #pragma unroll
    for (int j = 0; j < 3; ++j) {
      float v[8];
      #pragma unroll
      for (int e = 0; e < 8; ++e) {
        const int k = kbase + j * 8 + e;
        float t = 0.0f;
        if (k < KK_) {
          int c = k / 25, r = k - 25 * c, ki = r / 5, kj = r - 5 * ki;
          int ih = ihb + ki, iw = iwb + kj;
          if ((unsigned)ih < (unsigned)HW_ && (unsigned)iw < (unsigned)HW_)
            t = xb[(c * HW_ + ih) * HW_ + iw];
        }
        v[e] = t;
      }
      #pragma unroll
      for (int e = 0; e < 4; ++e)
        pk[j][e] = (unsigned)f2bf(v[2 * e]) | ((unsigned)f2bf(v[2 * e + 1]) << 16);
    }
  };
  auto stage_write = [&](int sel, const uint4v (&pk)[3]) {
    #pragma unroll
    for (int j = 0; j < 3; ++j) {
      int blk = wq * 3 + j;
      int blks = blk ^ (pos & 3);                 // involutive 16B-block swizzle
      *(uint4v*)&preS[sel][pos * KPAD + blks * 8] = pk[j];
    }
  };
  auto do_mfma = [&](int sel, float4v (&acc)[3][4]) {
    #pragma unroll
    for (int kt = 0; kt < 3; ++kt) {
      #pragma unroll
      for (int nt = 0; nt < 4; ++nt) {
        const int n = nt * 16 + col;
        const int blk = kt * 4 + g;
        short8v bfr = *(const short8v*)&preS[sel][n * KPAD + ((blk ^ (n & 3)) << 3)];
        #pragma unroll
        for (int mt = 0; mt < 3; ++mt)
          acc[mt][nt] = __builtin_amdgcn_mfma_f32_16x16x32_bf16(
              afr[mt][kt], bfr, acc[mt][nt], 0, 0, 0);
      }
    }
  };
  auto tile_tail = [&](int t, float4v (&acc)[3][4]) {
    const int blockl = base_l + t * 64;
    if (wq < 2) {
      // conv out: C/D layout col=lane&15, row=(lane>>4)*4+reg (m89-verified)
      #pragma unroll
      for (int mt = 0; mt < 3; ++mt)
        #pragma unroll
        for (int r = 0; r < 4; ++r) {
          const int ch = wq * 48 + mt * 16 + g * 4 + r;
          float* op = out + ((size_t)b * COUT_ + ch) * L_ + blockl + col;
          #pragma unroll
          for (int nt = 0; nt < 4; ++nt)
            __builtin_nontemporal_store(acc[mt][nt][r], &op[nt * 16]);
        }
    } else {
      float v1[4], v2[4]; int o1[4], o2[4];
      #pragma unroll
      for (int nt = 0; nt < 4; ++nt) {
        v1[nt] = -3.0e38f; v2[nt] = -3.0e38f;
        o1[nt] = 0x7fffffff; o2[nt] = 0x7fffffff;
        #pragma unroll
        for (int mt = 0; mt < 3; ++mt)
          #pragma unroll
          for (int r = 0; r < 4; ++r)
            ins2(acc[mt][nt][r], (wq - 2) * 48 + mt * 16 + g * 4 + r,
                 v1[nt], o1[nt], v2[nt], o2[nt]);
      }
      #pragma unroll
      for (int st = 0; st < 2; ++st) {       // butterfly over the 4 row-groups
        const int d = (st == 0) ? 16 : 32;
        #pragma unroll
        for (int nt = 0; nt < 4; ++nt) {
          float bv1 = __shfl_xor(v1[nt], d, 64);
          int   bo1 = __shfl_xor(o1[nt], d, 64);
          float bv2 = __shfl_xor(v2[nt], d, 64);
          int   bo2 = __shfl_xor(o2[nt], d, 64);
          ins2(bv1, bo1, v1[nt], o1[nt], v2[nt], o2[nt]);
          ins2(bv2, bo2, v1[nt], o1[nt], v2[nt], o2[nt]);
        }
      }
      if (g == 0) {
        #pragma unroll
        for (int nt = 0; nt < 4; ++nt)
          mrg[t & 1][wq - 2][nt * 16 + col] =
              make_float4(v1[nt], __int_as_float(o1[nt]),
                          v2[nt], __int_as_float(o2[nt]));
      }
    }
  };
  auto tile_merge = [&](int t) {
    if (tid < 64) {
      float4 m0 = mrg[t & 1][0][tid], m1 = mrg[t & 1][1][tid];
      float V1 = m0.x; int O1 = __float_as_int(m0.y);
      float V2 = m0.z; int O2 = __float_as_int(m0.w);
      ins2(m1.x, __float_as_int(m1.y), V1, O1, V2, O2);
      ins2(m1.z, __float_as_int(m1.w), V1, O1, V2, O2);
      top2[(size_t)b * L_ + base_l + t * 64 + tid] =
          make_float4(V1, __int_as_float(O1), V2, __int_as_float(O2));
    }
  };

  // ---- pipeline ----
  uint4v pk0[3], pk1[3];
  stage_load(0, pk0);
  stage_write(0, pk0);
  __syncthreads();

  float4v acc[3][4];
  #pragma unroll
  for (int mt = 0; mt < 3; ++mt)
    #pragma unroll
    for (int nt = 0; nt < 4; ++nt) acc[mt][nt] = (float4v)(0.0f);

  stage_load(1, pk1);        // issue tile-1 loads; latency hides under MFMA
  do_mfma(0, acc);
  stage_write(1, pk1);       // waitcnt + ds_write to the other buffer
  tile_tail(0, acc);
  __syncthreads();

  tile_merge(0);
  #pragma unroll
  for (int mt = 0; mt < 3; ++mt)
    #pragma unroll
    for (int nt = 0; nt < 4; ++nt) acc[mt][nt] = (float4v)(0.0f);
  do_mfma(1, acc);
  tile_tail(1, acc);
  __syncthreads();
  tile_merge(1);
}

// Kernel 2: yx/yy via MFMA — no per-k atomics (round-5 structure, unchanged).
__global__ __launch_bounds__(256, 1) void k2_gemm(
    const float* __restrict__ x, const float4* __restrict__ top2,
    float* __restrict__ part)
{
  __shared__ __align__(16) unsigned short actS[COUT_ * CL2];  // 48 KB
  __shared__ __align__(16) unsigned short preT[COUT_ * CL2];  // 48 KB
  __shared__ float yyS[COUT_];
  const int tid = threadIdx.x;
  const int b = blockIdx.y;
  const int pos = tid;
  const float* xb = x + (size_t)b * (3 * HW_ * HW_);

  {
    float4* a4 = (float4*)actS;
    float4* p4 = (float4*)preT;
    #pragma unroll
    for (int i = 0; i < 12; ++i) {
      a4[tid + i * 256] = make_float4(0, 0, 0, 0);
      p4[tid + i * 256] = make_float4(0, 0, 0, 0);
    }
    if (tid < COUT_) yyS[tid] = 0.0f;
  }
  __syncthreads();

  const int lane = tid & 63, w = tid >> 6;
  const int col = lane & 15, g = lane >> 4;
  const int mb = (w >> 1) * 48, nb = (w & 1) * 48;

  float4v acc[3][3];
  #pragma unroll
  for (int mt = 0; mt < 3; ++mt)
    #pragma unroll
    for (int nt = 0; nt < 3; ++nt) acc[mt][nt] = (float4v)(0.0f);

  int prevA = -1, prevB = -1;

  for (int ch = 0; ch < CPB2; ++ch) {
    const int l0 = (blockIdx.x * CPB2 + ch) * CL2;
    if (prevA >= 0) {
      *(unsigned short*)((char*)actS + prevA) = 0;
      *(unsigned short*)((char*)actS + prevB) = 0;
    }
    {
      float pre[KP_];
      im2col_load(xb, l0 + pos, pre);
      const int pblk = pos >> 3, plo = (pos & 7) << 1;
      #pragma unroll
      for (int k = 0; k < KK_; ++k) {
        int byteoff = k * 512 + ((pblk ^ (k & 7)) << 4) + plo;
        *(unsigned short*)((char*)preT + byteoff) = f2bf(pre[k]);
      }
      float4 t2 = top2[(size_t)b * L_ + l0 + pos];
      int o1 = __float_as_int(t2.y), o2 = __float_as_int(t2.w);
      prevA = o1 * 512 + ((pblk ^ (o1 & 7)) << 4) + plo;
      prevB = o2 * 512 + ((pblk ^ (o2 & 7)) << 4) + plo;
      *(unsigned short*)((char*)actS + prevA) = 0x3F80;        // bf16(1.0)
      *(unsigned short*)((char*)actS + prevB) = f2bf(DELTA_);
      atomicAdd(&yyS[o1], t2.x);
      atomicAdd(&yyS[o2], DELTA_ * t2.z);
    }
    __syncthreads();

    #pragma unroll
    for (int kt = 0; kt < 8; ++kt) {
      short8v a[3], bf[3];
      #pragma unroll
      for (int mt = 0; mt < 3; ++mt) {
        int row = mb + mt * 16 + col;
        a[mt] = *(const short8v*)((char*)actS + row * 512 +
                                  (((kt * 4 + g) ^ (row & 7)) << 4));
      }
      #pragma unroll
      for (int nt = 0; nt < 3; ++nt) {
        int row = nb + nt * 16 + col;
        bf[nt] = *(const short8v*)((char*)preT + row * 512 +
                                   (((kt * 4 + g) ^ (row & 7)) << 4));
      }
      #pragma unroll
      for (int mt = 0; mt < 3; ++mt)
        #pragma unroll
        for (int nt = 0; nt < 3; ++nt)
          acc[mt][nt] = __builtin_amdgcn_mfma_f32_16x16x32_bf16(
              a[mt], bf[nt], acc[mt][nt], 0, 0, 0);
    }
    __syncthreads();
  }

  float* prow = part + (size_t)(b * 3 + blockIdx.x) * PROW2;
  #pragma unroll
  for (int mt = 0; mt < 3; ++mt)
    #pragma unroll
    for (int nt = 0; nt < 3; ++nt)
      #pragma unroll
      for (int r = 0; r < 4; ++r) {
        int m = mb + mt * 16 + g * 4 + r;
        int n = nb + nt * 16 + col;
        prow[m * 96 + n] = acc[mt][nt][r];
      }
  if (tid < COUT_) prow[9216 + tid] = yyS[tid];
}

// Kernel 3: reduce 192 partial rows [9312] -> finals[7296] (drops kw pad cols).
__global__ __launch_bounds__(256) void k3_reduce(
    const float* __restrict__ part, float* __restrict__ finals)
{
  __shared__ float red[4][64];
  const int e = blockIdx.x * 64 + (threadIdx.x & 63);
  const int seg = threadIdx.x >> 6;
  float s = 0.0f;
  if (e < PROW2)
    for (int p = seg * (NPART2 / 4); p < (seg + 1) * (NPART2 / 4); ++p)
      s += part[(size_t)p * PROW2 + e];
  red[seg][threadIdx.x & 63] = s;
  __syncthreads();
  if (seg == 0 && e < PROW2) {
    int ll = threadIdx.x & 63;
    float t = (red[0][ll] + red[1][ll]) + (red[2][ll] + red[3][ll]);
    if (e < 9216) {
      int o = e / 96, kw = e - o * 96;
      if (kw < KK_) finals[o * KK_ + kw] = t;
    } else {
      finals[COUT_ * KK_ + (e - 9216)] = t;
    }
  }
}

// Kernel 4: ds = yx - yy*W; nc = max|ds|; new_W = W + LR*ds/nc.
__global__ __launch_bounds__(256) void k4_finalize(
    const float* __restrict__ w, const float* __restrict__ finals,
    float* __restrict__ outw)
{
  __shared__ float dsS[COUT_ * KK_];
  __shared__ float wmax[4];
  __shared__ float ncS;
  const int tid = threadIdx.x;
  float m = 0.0f;
  for (int i = tid; i < COUT_ * KK_; i += 256) {
    int o = i / KK_;
    float d = finals[i] - finals[COUT_ * KK_ + o] * w[i];
    dsS[i] = d;
    m = fmaxf(m, fabsf(d));
  }
  #pragma unroll
  for (int s = 32; s > 0; s >>= 1) m = fmaxf(m, __shfl_xor(m, s, 64));
  if ((tid & 63) == 0) wmax[tid >> 6] = m;
  __syncthreads();
  if (tid == 0) {
    float n = fmaxf(fmaxf(wmax[0], wmax[1]), fmaxf(wmax[2], wmax[3]));
    ncS = fmaxf(n, 1e-30f);
  }
  __syncthreads();
  const float scale = LR_ / ncS;
  for (int i = tid; i < COUT_ * KK_; i += 256) {
    outw[i] = w[i] + scale * dsS[i];
  }
}

extern "C" void kernel_launch(void* const* d_in, const int* in_sizes, int n_in,
                              void* d_out, int out_size, void* d_ws, size_t ws_size,
                              hipStream_t stream) {
  (void)in_sizes; (void)n_in; (void)out_size; (void)ws_size;
  const float* x = (const float*)d_in[0];   // [64,3,96,96]
  const float* w = (const float*)d_in[1];   // [96,3,5,5]
  float* out  = (float*)d_out;              // conv out [64,96,48,48]
  float* outw = out + OUT_ELEMS;            // new_weight [96,75]

  unsigned short* wbf = (unsigned short*)d_ws;               // [192*96] bf16
  float4* top2 = (float4*)((char*)d_ws + 192 * KPAD * 2);    // [64*2304]
  float*  part = (float*)((char*)top2 + (size_t)B_ * L_ * sizeof(float4)); // [192][9312]
  float*  finals = part + (size_t)NPART2 * PROW2;            // [7296]

  k0_prep   <<<dim3((192 * KPAD + 255) / 256), 256, 0, stream>>>(w, wbf);
  k1_mfma   <<<dim3(L_ / (64 * NT1), B_), 256, 0, stream>>>(x, wbf, out, top2);
  k2_gemm   <<<dim3(3, B_), 256, 0, stream>>>(x, top2, part);
  k3_reduce <<<dim3((PROW2 + 63) / 64), 256, 0, stream>>>(part, finals);
  k4_finalize<<<dim3(1), 256, 0, stream>>>(w, finals, outw);
}

// Round 7
// 116.028 us; speedup vs baseline: 1.6057x; 1.6057x over previous
//
#include <hip/hip_runtime.h>

// Problem constants
#define B_     64
#define HW_    96
#define COUT_  96
#define KK_    75          // CIN*KH*KW
#define KP_    76          // padded K for fp32 im2col (k2)
#define KPAD   96          // padded K for MFMA (3 x 32)
#define HOUT_  48
#define L_     2304        // 48*48
#define LR_    0.02f
#define DELTA_ -0.4f
#define OUT_ELEMS (B_*COUT_*L_)
#define CL2    256                  // k2 l-chunk size
#define CPB2   3                    // l-chunks per k2 block
#define NPART2 (B_*3)               // 192 partial rows
#define PROW2  (COUT_*96 + COUT_)   // 9312 floats: yx[96][96] + yy[96]
#define CPI    144                  // 16-position chunks per image (2304/16)

typedef __attribute__((ext_vector_type(8))) short short8v;     // 8 bf16
typedef __attribute__((ext_vector_type(4))) float float4v;     // 4 f32 acc
typedef __attribute__((ext_vector_type(4))) unsigned uint4v;   // 16B pack

__device__ __forceinline__ unsigned short f2bf(float f) {  // RNE f32->bf16
  unsigned u = __float_as_uint(f);
  u += 0x7fff + ((u >> 16) & 1);
  return (unsigned short)(u >> 16);
}

// top-2 insert with lax.top_k tiebreak (equal values -> lower channel index)
__device__ __forceinline__ void ins2(float v, int o, float& v1, int& o1,
                                     float& v2, int& o2) {
  bool b1 = (v > v1) || (v == v1 && o < o1);
  bool b2 = (v > v2) || (v == v2 && o < o2);
  if (b1)      { v2 = v1; o2 = o1; v1 = v; o1 = o; }
  else if (b2) { v2 = v;  o2 = o; }
}

__device__ __forceinline__ void im2col_load(const float* __restrict__ xb, int l,
                                            float* __restrict__ pre) {
  const int oh = l / HOUT_, ow = l - oh * HOUT_;
  #pragma unroll
  for (int c = 0; c < 3; ++c) {
    #pragma unroll
    for (int i = 0; i < 5; ++i) {
      int ih = oh * 2 + i - 2;
      bool okh = ((unsigned)ih < (unsigned)HW_);
      #pragma unroll
      for (int j = 0; j < 5; ++j) {
        int iw = ow * 2 + j - 2;
        float v = 0.0f;
        if (okh && ((unsigned)iw < (unsigned)HW_)) v = xb[(c * HW_ + ih) * HW_ + iw];
        pre[c * 25 + i * 5 + j] = v;
      }
    }
  }
  pre[KK_] = 0.0f;
}

// Kernel 0: build stacked bf16 A-matrix [192][96]: rows 0..95 = W, 96..191 = W*|W|.
__global__ __launch_bounds__(256) void k0_prep(const float* __restrict__ w,
                                               unsigned short* __restrict__ wbf) {
  int i = blockIdx.x * 256 + threadIdx.x;
  if (i >= 192 * KPAD) return;
  int row = i / KPAD, k = i - row * KPAD;
  float v = 0.0f;
  if (k < KK_) {
    float ww = w[(row % COUT_) * KK_ + k];
    v = (row < COUT_) ? ww : ww * fabsf(ww);   // sign(w)|w|^2, p=3
  }
  wbf[i] = f2bf(v);
}

// Kernel 1 (v4): WAVE-INDEPENDENT MFMA conv + tot + top-2.
// Zero LDS, zero barriers. Each wave owns 16 positions x all 192 stacked rows:
//   B-frag built per-lane straight from x (110KB/image -> L1/L2-resident);
//   A-frags streamed from 36KB L1-resident wbf inside the mt loop (4 VGPRs);
//   36 MFMAs into acc[12]; W half stored, Wp half -> in-wave top-2 butterfly.
// 9216 independent waves, ~90 VGPR -> 4 waves/SIMD, nothing to convoy.
__global__ __launch_bounds__(256, 4) void k1_mfma(
    const float* __restrict__ x, const unsigned short* __restrict__ wbf,
    float* __restrict__ out, float4* __restrict__ top2)
{
  const int tid = threadIdx.x;
  const int lane = tid & 63, wq = tid >> 6;
  const int gid = blockIdx.x * 4 + wq;          // 0..9215
  const int b = gid / CPI;
  const int chunk = gid - b * CPI;
  const int l0 = chunk * 16;
  const int col = lane & 15, g = lane >> 4;
  const float* xb = x + (size_t)b * (3 * HW_ * HW_);

  const int l = l0 + col;
  const int oh = l / HOUT_, ow = l - oh * HOUT_;
  const int ihb = 2 * oh - 2, iwb = 2 * ow - 2;

  // B fragments: lane (col=position, g) holds k = kt*32 + g*8 + e, e=0..7
  short8v bfr[3];
  #pragma unroll
  for (int kt = 0; kt < 3; ++kt) {
    uint4v pk;
    #pragma unroll
    for (int e2 = 0; e2 < 4; ++e2) {
      float v0 = 0.0f, v1 = 0.0f;
      const int k0 = kt * 32 + g * 8 + 2 * e2;
      if (k0 < KK_) {
        int c = k0 / 25, r = k0 - 25 * c, ki = r / 5, kj = r - 5 * ki;
        int ih = ihb + ki, iw = iwb + kj;
        if ((unsigned)ih < (unsigned)HW_ && (unsigned)iw < (unsigned)HW_)
          v0 = xb[(c * HW_ + ih) * HW_ + iw];
      }
      const int k1e = k0 + 1;
      if (k1e < KK_) {
        int c = k1e / 25, r = k1e - 25 * c, ki = r / 5, kj = r - 5 * ki;
        int ih = ihb + ki, iw = iwb + kj;
        if ((unsigned)ih < (unsigned)HW_ && (unsigned)iw < (unsigned)HW_)
          v1 = xb[(c * HW_ + ih) * HW_ + iw];
      }
      pk[e2] = (unsigned)f2bf(v0) | ((unsigned)f2bf(v1) << 16);
    }
    bfr[kt] = __builtin_bit_cast(short8v, pk);
  }

  // MFMA: acc[mt] covers stacked rows [mt*16, mt*16+16) x 16 positions.
  // A-frag row = mt*16 + col, k = kt*32 + g*8 + j (layout matched to rounds 4-6).
  float4v acc[12];
  #pragma unroll
  for (int mt = 0; mt < 12; ++mt) acc[mt] = (float4v)(0.0f);
  #pragma unroll
  for (int kt = 0; kt < 3; ++kt) {
    #pragma unroll
    for (int mt = 0; mt < 12; ++mt) {
      short8v afr = *(const short8v*)(
          wbf + ((mt * 16 + col) * KPAD + kt * 32 + g * 8));
      acc[mt] = __builtin_amdgcn_mfma_f32_16x16x32_bf16(
          afr, bfr[kt], acc[mt], 0, 0, 0);
    }
  }

  // W half (rows 0..95): direct store. C/D: col(pos)=lane&15, row=g*4+r (m89).
  #pragma unroll
  for (int mt = 0; mt < 6; ++mt) {
    #pragma unroll
    for (int r = 0; r < 4; ++r) {
      const int ch = mt * 16 + g * 4 + r;
      out[((size_t)b * COUT_ + ch) * L_ + l0 + col] = acc[mt][r];
    }
  }

  // Wp half (rows 96..191): per-position top-2 over 96 channels.
  float v1 = -3.0e38f, v2 = -3.0e38f;
  int o1 = 0x7fffffff, o2 = 0x7fffffff;
  #pragma unroll
  for (int mt = 6; mt < 12; ++mt)
    #pragma unroll
    for (int r = 0; r < 4; ++r)
      ins2(acc[mt][r], (mt - 6) * 16 + g * 4 + r, v1, o1, v2, o2);
  #pragma unroll
  for (int st = 0; st < 2; ++st) {     // butterfly across the 4 g-groups
    const int d = (st == 0) ? 16 : 32;
    float bv1 = __shfl_xor(v1, d, 64);
    int   bo1 = __shfl_xor(o1, d, 64);
    float bv2 = __shfl_xor(v2, d, 64);
    int   bo2 = __shfl_xor(o2, d, 64);
    ins2(bv1, bo1, v1, o1, v2, o2);
    ins2(bv2, bo2, v1, o1, v2, o2);
  }
  if (g == 0)
    top2[(size_t)b * L_ + l0 + col] =
        make_float4(v1, __int_as_float(o1), v2, __int_as_float(o2));
}

// Kernel 2: yx/yy via MFMA — no per-k atomics (round-5 structure, unchanged).
__global__ __launch_bounds__(256, 1) void k2_gemm(
    const float* __restrict__ x, const float4* __restrict__ top2,
    float* __restrict__ part)
{
  __shared__ __align__(16) unsigned short actS[COUT_ * CL2];  // 48 KB
  __shared__ __align__(16) unsigned short preT[COUT_ * CL2];  // 48 KB
  __shared__ float yyS[COUT_];
  const int tid = threadIdx.x;
  const int b = blockIdx.y;
  const int pos = tid;
  const float* xb = x + (size_t)b * (3 * HW_ * HW_);

  {
    float4* a4 = (float4*)actS;
    float4* p4 = (float4*)preT;
    #pragma unroll
    for (int i = 0; i < 12; ++i) {
      a4[tid + i * 256] = make_float4(0, 0, 0, 0);
      p4[tid + i * 256] = make_float4(0, 0, 0, 0);
    }
    if (tid < COUT_) yyS[tid] = 0.0f;
  }
  __syncthreads();

  const int lane = tid & 63, w = tid >> 6;
  const int col = lane & 15, g = lane >> 4;
  const int mb = (w >> 1) * 48, nb = (w & 1) * 48;

  float4v acc[3][3];
  #pragma unroll
  for (int mt = 0; mt < 3; ++mt)
    #pragma unroll
    for (int nt = 0; nt < 3; ++nt) acc[mt][nt] = (float4v)(0.0f);

  int prevA = -1, prevB = -1;

  for (int ch = 0; ch < CPB2; ++ch) {
    const int l0 = (blockIdx.x * CPB2 + ch) * CL2;
    if (prevA >= 0) {
      *(unsigned short*)((char*)actS + prevA) = 0;
      *(unsigned short*)((char*)actS + prevB) = 0;
    }
    {
      float pre[KP_];
      im2col_load(xb, l0 + pos, pre);
      const int pblk = pos >> 3, plo = (pos & 7) << 1;
      #pragma unroll
      for (int k = 0; k < KK_; ++k) {
        int byteoff = k * 512 + ((pblk ^ (k & 7)) << 4) + plo;
        *(unsigned short*)((char*)preT + byteoff) = f2bf(pre[k]);
      }
      float4 t2 = top2[(size_t)b * L_ + l0 + pos];
      int o1 = __float_as_int(t2.y), o2 = __float_as_int(t2.w);
      prevA = o1 * 512 + ((pblk ^ (o1 & 7)) << 4) + plo;
      prevB = o2 * 512 + ((pblk ^ (o2 & 7)) << 4) + plo;
      *(unsigned short*)((char*)actS + prevA) = 0x3F80;        // bf16(1.0)
      *(unsigned short*)((char*)actS + prevB) = f2bf(DELTA_);
      atomicAdd(&yyS[o1], t2.x);
      atomicAdd(&yyS[o2], DELTA_ * t2.z);
    }
    __syncthreads();

    #pragma unroll
    for (int kt = 0; kt < 8; ++kt) {
      short8v a[3], bf[3];
      #pragma unroll
      for (int mt = 0; mt < 3; ++mt) {
        int row = mb + mt * 16 + col;
        a[mt] = *(const short8v*)((char*)actS + row * 512 +
                                  (((kt * 4 + g) ^ (row & 7)) << 4));
      }
      #pragma unroll
      for (int nt = 0; nt < 3; ++nt) {
        int row = nb + nt * 16 + col;
        bf[nt] = *(const short8v*)((char*)preT + row * 512 +
                                   (((kt * 4 + g) ^ (row & 7)) << 4));
      }
      #pragma unroll
      for (int mt = 0; mt < 3; ++mt)
        #pragma unroll
        for (int nt = 0; nt < 3; ++nt)
          acc[mt][nt] = __builtin_amdgcn_mfma_f32_16x16x32_bf16(
              a[mt], bf[nt], acc[mt][nt], 0, 0, 0);
    }
    __syncthreads();
  }

  float* prow = part + (size_t)(b * 3 + blockIdx.x) * PROW2;
  #pragma unroll
  for (int mt = 0; mt < 3; ++mt)
    #pragma unroll
    for (int nt = 0; nt < 3; ++nt)
      #pragma unroll
      for (int r = 0; r < 4; ++r) {
        int m = mb + mt * 16 + g * 4 + r;
        int n = nb + nt * 16 + col;
        prow[m * 96 + n] = acc[mt][nt][r];
      }
  if (tid < COUT_) prow[9216 + tid] = yyS[tid];
}

// Kernel 3: reduce 192 partial rows [9312] -> finals[7296] (drops kw pad cols).
__global__ __launch_bounds__(256) void k3_reduce(
    const float* __restrict__ part, float* __restrict__ finals)
{
  __shared__ float red[4][64];
  const int e = blockIdx.x * 64 + (threadIdx.x & 63);
  const int seg = threadIdx.x >> 6;
  float s = 0.0f;
  if (e < PROW2)
    for (int p = seg * (NPART2 / 4); p < (seg + 1) * (NPART2 / 4); ++p)
      s += part[(size_t)p * PROW2 + e];
  red[seg][threadIdx.x & 63] = s;
  __syncthreads();
  if (seg == 0 && e < PROW2) {
    int ll = threadIdx.x & 63;
    float t = (red[0][ll] + red[1][ll]) + (red[2][ll] + red[3][ll]);
    if (e < 9216) {
      int o = e / 96, kw = e - o * 96;
      if (kw < KK_) finals[o * KK_ + kw] = t;
    } else {
      finals[COUT_ * KK_ + (e - 9216)] = t;
    }
  }
}

// Kernel 4: ds = yx - yy*W; nc = max|ds|; new_W = W + LR*ds/nc.
__global__ __launch_bounds__(256) void k4_finalize(
    const float* __restrict__ w, const float* __restrict__ finals,
    float* __restrict__ outw)
{
  __shared__ float dsS[COUT_ * KK_];
  __shared__ float wmax[4];
  __shared__ float ncS;
  const int tid = threadIdx.x;
  float m = 0.0f;
  for (int i = tid; i < COUT_ * KK_; i += 256) {
    int o = i / KK_;
    float d = finals[i] - finals[COUT_ * KK_ + o] * w[i];
    dsS[i] = d;
    m = fmaxf(m, fabsf(d));
  }
  #pragma unroll
  for (int s = 32; s > 0; s >>= 1) m = fmaxf(m, __shfl_xor(m, s, 64));
  if ((tid & 63) == 0) wmax[tid >> 6] = m;
  __syncthreads();
  if (tid == 0) {
    float n = fmaxf(fmaxf(wmax[0], wmax[1]), fmaxf(wmax[2], wmax[3]));
    ncS = fmaxf(n, 1e-30f);
  }
  __syncthreads();
  const float scale = LR_ / ncS;
  for (int i = tid; i < COUT_ * KK_; i += 256) {
    outw[i] = w[i] + scale * dsS[i];
  }
}

extern "C" void kernel_launch(void* const* d_in, const int* in_sizes, int n_in,
                              void* d_out, int out_size, void* d_ws, size_t ws_size,
                              hipStream_t stream) {
  (void)in_sizes; (void)n_in; (void)out_size; (void)ws_size;
  const float* x = (const float*)d_in[0];   // [64,3,96,96]
  const float* w = (const float*)d_in[1];   // [96,3,5,5]
  float* out  = (float*)d_out;              // conv out [64,96,48,48]
  float* outw = out + OUT_ELEMS;            // new_weight [96,75]

  unsigned short* wbf = (unsigned short*)d_ws;               // [192*96] bf16
  float4* top2 = (float4*)((char*)d_ws + 192 * KPAD * 2);    // [64*2304]
  float*  part = (float*)((char*)top2 + (size_t)B_ * L_ * sizeof(float4)); // [192][9312]
  float*  finals = part + (size_t)NPART2 * PROW2;            // [7296]

  k0_prep   <<<dim3((192 * KPAD + 255) / 256), 256, 0, stream>>>(w, wbf);
  k1_mfma   <<<dim3(B_ * CPI / 4), 256, 0, stream>>>(x, wbf, out, top2);
  k2_gemm   <<<dim3(3, B_), 256, 0, stream>>>(x, top2, part);
  k3_reduce <<<dim3((PROW2 + 63) / 64), 256, 0, stream>>>(part, finals);
  k4_finalize<<<dim3(1), 256, 0, stream>>>(w, finals, outw);
}